// Round 1
// baseline (270.062 us; speedup 1.0000x reference)
//
#include <hip/hip_runtime.h>
#include <hip/hip_bf16.h>

typedef short short8 __attribute__((ext_vector_type(8)));
typedef short short4v __attribute__((ext_vector_type(4)));
typedef float f32x4 __attribute__((ext_vector_type(4)));

// Problem constants: B=2, T=2048, E=1024, H=16, D=64
// BT = 4096 rows, N3 = 3072 qkv cols, K = 1024

__device__ __forceinline__ short bf16r(float f) {
  unsigned int u = __builtin_bit_cast(unsigned int, f);
  unsigned int r = (u + 0x7fffu + ((u >> 16) & 1u)) >> 16;   // RNE
  return (short)r;
}

__device__ __forceinline__ void gload_lds16(const void* g, void* l) {
  __builtin_amdgcn_global_load_lds(
      (const __attribute__((address_space(1))) unsigned int*)g,
      (__attribute__((address_space(3))) unsigned int*)l, 16, 0, 0);
}

// ---------------- f32 -> bf16 convert (vectorized) ----------------
__global__ void cvt_bf16_k(const float* __restrict__ src, short* __restrict__ dst, int n) {
  int stride = gridDim.x * blockDim.x;
  for (int i = blockIdx.x * blockDim.x + threadIdx.x; i * 4 < n; i += stride) {
    float4 v = reinterpret_cast<const float4*>(src)[i];
    short4v o = { bf16r(v.x), bf16r(v.y), bf16r(v.z), bf16r(v.w) };
    reinterpret_cast<short4v*>(dst)[i] = o;
  }
}

// ---------------- RoPE cos/sin table: tab[t*32+j] = (cos, sin) of t/theta^(j/32) ----------------
__global__ void rope_tab_k(float2* __restrict__ tab) {
  int idx = blockIdx.x * blockDim.x + threadIdx.x;  // 2048*32 = 65536
  int t = idx >> 5, j = idx & 31;
  float freq = 1.0f / powf(10000.0f, (float)j * (1.0f / 32.0f));
  float ang = (float)t * freq;
  tab[idx] = make_float2(cosf(ang), sinf(ang));
}

// ---------------- QKV GEMM: C[4096,3072] = x @ W^T + b, fused RoPE + scatter to q/k/v ----------------
__launch_bounds__(256, 2)
__global__ void qkv_gemm_k(const short* __restrict__ xb, const short* __restrict__ wb,
                           const float* __restrict__ bias, const float2* __restrict__ tab,
                           short* __restrict__ qb, short* __restrict__ kb, short* __restrict__ vb) {
  __shared__ short lA[128 * 64];
  __shared__ short lB[128 * 64];
  const int tid = threadIdx.x;
  const int l = tid & 63, w = tid >> 6;
  const int wr = w >> 1, wc = w & 1;
  const int l15 = l & 15, lg = l >> 4;

  int bid = blockIdx.x;
  int swz = (bid & 7) * 96 + (bid >> 3);   // 768 blocks -> XCD-contiguous, bijective
  int tm = swz / 24, tn = swz % 24;        // 32 x 24 tiles of 128x128

  f32x4 acc[4][4] = {};

  for (int kt = 0; kt < 16; ++kt) {
    const int k0 = kt * 64;
    __syncthreads();
#pragma unroll
    for (int p = 0; p < 4; ++p) {          // A tile 128x64 bf16, source pre-swizzled chunks
      int idx = p * 256 + tid;
      int row = idx >> 3, ch = idx & 7;
      int gch = ch ^ (row & 7);
      gload_lds16(xb + (tm * 128 + row) * 1024 + k0 + gch * 8, (char*)lA + idx * 16);
    }
#pragma unroll
    for (int p = 0; p < 4; ++p) {          // B tile (W rows) 128x64
      int idx = p * 256 + tid;
      int row = idx >> 3, ch = idx & 7;
      int gch = ch ^ (row & 7);
      gload_lds16(wb + (tn * 128 + row) * 1024 + k0 + gch * 8, (char*)lB + idx * 16);
    }
    __syncthreads();
#pragma unroll
    for (int kc = 0; kc < 2; ++kc) {
      short8 af[4], bfr[4];
#pragma unroll
      for (int m = 0; m < 4; ++m) {
        int row = wr * 64 + m * 16 + l15;
        int ch = (kc * 4 + lg) ^ (row & 7);
        af[m] = *reinterpret_cast<const short8*>((const char*)lA + row * 128 + ch * 16);
      }
#pragma unroll
      for (int n = 0; n < 4; ++n) {
        int row = wc * 64 + n * 16 + l15;
        int ch = (kc * 4 + lg) ^ (row & 7);
        bfr[n] = *reinterpret_cast<const short8*>((const char*)lB + row * 128 + ch * 16);
      }
#pragma unroll
      for (int m = 0; m < 4; ++m)
#pragma unroll
        for (int n = 0; n < 4; ++n)
          acc[m][n] = __builtin_amdgcn_mfma_f32_16x16x32_bf16(af[m], bfr[n], acc[m][n], 0, 0, 0);
    }
  }

  // Epilogue: bias + RoPE (q,k) + 1/sqrt(D) into q + scatter bf16 to [BH][T][D]
  const int sec = tn >> 3;   // 1024-col sections: 0=q 1=k 2=v (BN=128 never straddles)
#pragma unroll
  for (int m = 0; m < 4; ++m) {
#pragma unroll
    for (int n = 0; n < 4; ++n) {
      int gcol = tn * 128 + wc * 64 + n * 16 + l15;
      float bv = bias[gcol];
      int colin = gcol & 1023;
      int h = colin >> 6, d = colin & 63;
      f32x4 v = acc[m][n];
#pragma unroll
      for (int i = 0; i < 4; ++i) v[i] += bv;
      int rbase = tm * 128 + wr * 64 + m * 16 + lg * 4;
      if (sec == 2) {
#pragma unroll
        for (int i = 0; i < 4; ++i) {
          int grow = rbase + i;
          int b = grow >> 11, t = grow & 2047;
          vb[(((b * 16 + h) * 2048 + t) << 6) + d] = bf16r(v[i]);
        }
      } else {
        int j = d >> 1;
        bool odd = d & 1;
        short* dst = (sec == 0) ? qb : kb;
        float scale = (sec == 0) ? 0.125f : 1.0f;  // fold 1/sqrt(64) into q (exact pow2)
#pragma unroll
        for (int i = 0; i < 4; ++i) {
          int grow = rbase + i;
          int t = grow & 2047;
          float2 cs = tab[t * 32 + j];
          float part = __shfl_xor(v[i], 1);        // pair feature lives in adjacent lane
          float nv = odd ? (cs.y * part + cs.x * v[i]) : (cs.x * v[i] - cs.y * part);
          int b = grow >> 11;
          dst[(((b * 16 + h) * 2048 + t) << 6) + d] = bf16r(nv * scale);
        }
      }
    }
  }
}

// ---------------- Flash attention: one (b,h), 64 q-rows per block, 4 waves x 16 rows ----------------
__launch_bounds__(256, 2)
__global__ void attn_k(const short* __restrict__ qb, const short* __restrict__ kb,
                       const short* __restrict__ vb, float* __restrict__ out) {
  __shared__ short lK[64 * 64];        // [kv][d], chunk-XOR swizzled via source
  __shared__ short lVT[64 * 72];       // [d][kv], stride 72 pad (16B-aligned rows)
  __shared__ short lP[4][16 * 72];     // per-wave P round-trip, stride 72
  const int tid = threadIdx.x, l = tid & 63, w = tid >> 6;
  const int l15 = l & 15, lg = l >> 4;
  const int qt = blockIdx.x, bh = blockIdx.y;

  // Q fragments in registers (q pre-scaled by 1/8)
  const short* qptr = qb + (bh * 2048 + qt * 64 + w * 16) * 64;
  short8 qf[2];
#pragma unroll
  for (int kc = 0; kc < 2; ++kc)
    qf[kc] = *reinterpret_cast<const short8*>(qptr + l15 * 64 + kc * 32 + lg * 8);

  f32x4 o[4] = {};
  float mrow[4], lrow[4];
#pragma unroll
  for (int i = 0; i < 4; ++i) { mrow[i] = -1e30f; lrow[i] = 0.f; }

  const short* kbase = kb + bh * 2048 * 64;
  const short* vbase = vb + bh * 2048 * 64;
  short* pw = lP[w];

  for (int kt = 0; kt < 32; ++kt) {
    __syncthreads();
#pragma unroll
    for (int p = 0; p < 2; ++p) {       // K tile 64x64 via global_load_lds, pre-swizzled source
      int idx = p * 256 + tid;
      int row = idx >> 3, ch = idx & 7;
      int gch = ch ^ (row & 7);
      gload_lds16(kbase + (kt * 64 + row) * 64 + gch * 8, (char*)lK + idx * 16);
    }
#pragma unroll
    for (int p = 0; p < 2; ++p) {       // V tile reg-staged TRANSPOSED into lVT[d][kv]
      int idx = p * 256 + tid;
      int row = idx >> 3, c0 = (idx & 7) * 8;
      short8 vr = *reinterpret_cast<const short8*>(vbase + (kt * 64 + row) * 64 + c0);
#pragma unroll
      for (int e = 0; e < 8; ++e)
        lVT[(c0 + e) * 72 + row] = vr[e];
    }
    __syncthreads();

    // S = Q K^T  (scaled already), C-frag: row=(lg*4+i) q, col=n*16+l15 kv
    f32x4 s[4] = {};
#pragma unroll
    for (int kc = 0; kc < 2; ++kc)
#pragma unroll
      for (int n = 0; n < 4; ++n) {
        int row = n * 16 + l15;
        int ch = (kc * 4 + lg) ^ (row & 7);
        short8 kf = *reinterpret_cast<const short8*>((const char*)lK + row * 128 + ch * 16);
        s[n] = __builtin_amdgcn_mfma_f32_16x16x32_bf16(qf[kc], kf, s[n], 0, 0, 0);
      }

    // online softmax (wave-parallel row reduce over 16 lanes + 4 reg-tiles)
    float rmax[4];
#pragma unroll
    for (int i = 0; i < 4; ++i)
      rmax[i] = fmaxf(fmaxf(s[0][i], s[1][i]), fmaxf(s[2][i], s[3][i]));
#pragma unroll
    for (int msk = 1; msk <= 8; msk <<= 1)
#pragma unroll
      for (int i = 0; i < 4; ++i)
        rmax[i] = fmaxf(rmax[i], __shfl_xor(rmax[i], msk));

    float corr[4];
#pragma unroll
    for (int i = 0; i < 4; ++i) {
      float mn = fmaxf(mrow[i], rmax[i]);
      corr[i] = __expf(mrow[i] - mn);
      mrow[i] = mn;
    }
#pragma unroll
    for (int n = 0; n < 4; ++n)
#pragma unroll
      for (int i = 0; i < 4; ++i)
        s[n][i] = __expf(s[n][i] - mrow[i]);

    float rsum[4];
#pragma unroll
    for (int i = 0; i < 4; ++i)
      rsum[i] = (s[0][i] + s[1][i]) + (s[2][i] + s[3][i]);
#pragma unroll
    for (int msk = 1; msk <= 8; msk <<= 1)
#pragma unroll
      for (int i = 0; i < 4; ++i)
        rsum[i] += __shfl_xor(rsum[i], msk);
#pragma unroll
    for (int i = 0; i < 4; ++i)
      lrow[i] = lrow[i] * corr[i] + rsum[i];
#pragma unroll
    for (int dt = 0; dt < 4; ++dt)
#pragma unroll
      for (int i = 0; i < 4; ++i)
        o[dt][i] *= corr[i];

    // P (bf16) -> per-wave LDS to convert C-frag layout to A-frag layout
#pragma unroll
    for (int n = 0; n < 4; ++n)
#pragma unroll
      for (int i = 0; i < 4; ++i)
        pw[(lg * 4 + i) * 72 + n * 16 + l15] = bf16r(s[n][i]);

    // O += P V
#pragma unroll
    for (int kc = 0; kc < 2; ++kc) {
      short8 pa = *reinterpret_cast<const short8*>(pw + l15 * 72 + kc * 32 + lg * 8);
#pragma unroll
      for (int dt = 0; dt < 4; ++dt) {
        short8 vf = *reinterpret_cast<const short8*>(lVT + (dt * 16 + l15) * 72 + kc * 32 + lg * 8);
        o[dt] = __builtin_amdgcn_mfma_f32_16x16x32_bf16(pa, vf, o[dt], 0, 0, 0);
      }
    }
  }

  const int b = bh >> 4, h = bh & 15;
#pragma unroll
  for (int i = 0; i < 4; ++i) {
    int t = qt * 64 + w * 16 + lg * 4 + i;
    float inv = 1.0f / lrow[i];
    float* op = out + (b * 2048 + t) * 1024 + h * 64;
#pragma unroll
    for (int dt = 0; dt < 4; ++dt)
      op[dt * 16 + l15] = o[dt][i] * inv;
  }
}

// ---------------- launch ----------------
extern "C" void kernel_launch(void* const* d_in, const int* in_sizes, int n_in,
                              void* d_out, int out_size, void* d_ws, size_t ws_size,
                              hipStream_t stream) {
  const float* x    = (const float*)d_in[0];   // [2,2048,1024]
  const float* W    = (const float*)d_in[1];   // [3072,1024]
  const float* bias = (const float*)d_in[2];   // [3072]
  float* out = (float*)d_out;
  char* ws = (char*)d_ws;

  short*  xb   = (short*) (ws);                  //  8 MiB: x bf16
  short*  wb   = (short*) (ws + 8388608);        //  6 MiB: W bf16
  short*  qbuf = (short*) (ws + 14680064);       //  8 MiB: q [BH][T][D] bf16 (pre-scaled)
  short*  kbuf = (short*) (ws + 23068672);       //  8 MiB
  short*  vbuf = (short*) (ws + 31457280);       //  8 MiB
  float2* tab  = (float2*)(ws + 39845888);       //  512 KiB rope table

  hipLaunchKernelGGL(cvt_bf16_k, dim3(2048), dim3(256), 0, stream, x, xb, 4194304);
  hipLaunchKernelGGL(cvt_bf16_k, dim3(1536), dim3(256), 0, stream, W, wb, 3145728);
  hipLaunchKernelGGL(rope_tab_k, dim3(256), dim3(256), 0, stream, tab);
  hipLaunchKernelGGL(qkv_gemm_k, dim3(768), dim3(256), 0, stream,
                     xb, wb, bias, tab, qbuf, kbuf, vbuf);
  hipLaunchKernelGGL(attn_k, dim3(32, 32), dim3(256), 0, stream, qbuf, kbuf, vbuf, out);
}

// Round 2
// 172.059 us; speedup vs baseline: 1.5696x; 1.5696x over previous
//
#include <hip/hip_runtime.h>
#include <hip/hip_bf16.h>

typedef short short8 __attribute__((ext_vector_type(8)));
typedef short short4v __attribute__((ext_vector_type(4)));
typedef float f32x4 __attribute__((ext_vector_type(4)));

// Problem constants: B=2, T=2048, E=1024, H=16, D=64

__device__ __forceinline__ short bf16r(float f) {
  unsigned int u = __builtin_bit_cast(unsigned int, f);
  unsigned int r = (u + 0x7fffu + ((u >> 16) & 1u)) >> 16;   // RNE
  return (short)r;
}

// pack two f32 -> bf16x2 (round-half-up: <=0.5 ulp, bias only at exact ties)
__device__ __forceinline__ unsigned int packbf2(float a, float b) {
  unsigned int ua = __builtin_bit_cast(unsigned int, a);
  unsigned int ub = __builtin_bit_cast(unsigned int, b);
  return ((ua + 0x8000u) >> 16) | ((ub + 0x8000u) & 0xffff0000u);
}

__device__ __forceinline__ float fast_exp2(float x) {
#if __has_builtin(__builtin_amdgcn_exp2f)
  return __builtin_amdgcn_exp2f(x);
#else
  return exp2f(x);
#endif
}

__device__ __forceinline__ void gload_lds16(const void* g, void* l) {
  __builtin_amdgcn_global_load_lds(
      (const __attribute__((address_space(1))) unsigned int*)g,
      (__attribute__((address_space(3))) unsigned int*)l, 16, 0, 0);
}

// ---------------- f32 -> bf16 convert (vectorized) ----------------
__global__ void cvt_bf16_k(const float* __restrict__ src, short* __restrict__ dst, int n) {
  int stride = gridDim.x * blockDim.x;
  for (int i = blockIdx.x * blockDim.x + threadIdx.x; i * 4 < n; i += stride) {
    float4 v = reinterpret_cast<const float4*>(src)[i];
    short4v o = { bf16r(v.x), bf16r(v.y), bf16r(v.z), bf16r(v.w) };
    reinterpret_cast<short4v*>(dst)[i] = o;
  }
}

// ---------------- RoPE cos/sin table ----------------
__global__ void rope_tab_k(float2* __restrict__ tab) {
  int idx = blockIdx.x * blockDim.x + threadIdx.x;  // 2048*32
  int t = idx >> 5, j = idx & 31;
  float freq = 1.0f / powf(10000.0f, (float)j * (1.0f / 32.0f));
  float ang = (float)t * freq;
  tab[idx] = make_float2(cosf(ang), sinf(ang));
}

// ---------------- QKV GEMM: C[4096,3072] = x @ W^T + b, fused RoPE + scatter ----------------
// q -> [bh][t][d] bf16, pre-scaled by (1/8)*log2(e)  (softmax done in base 2)
// k -> [bh][t][d] bf16
// v -> TRANSPOSED [bh][d][t] bf16 (so attention needs no LDS transpose)
__launch_bounds__(256, 2)
__global__ void qkv_gemm_k(const short* __restrict__ xb, const short* __restrict__ wb,
                           const float* __restrict__ bias, const float2* __restrict__ tab,
                           short* __restrict__ qb, short* __restrict__ kb, short* __restrict__ vb) {
  __shared__ short lA[128 * 64];
  __shared__ short lB[128 * 64];
  const int tid = threadIdx.x;
  const int l = tid & 63, w = tid >> 6;
  const int wr = w >> 1, wc = w & 1;
  const int l15 = l & 15, lg = l >> 4;

  int bid = blockIdx.x;
  int swz = (bid & 7) * 96 + (bid >> 3);   // 768 blocks, bijective XCD swizzle
  int tm = swz / 24, tn = swz % 24;

  f32x4 acc[4][4] = {};

  for (int kt = 0; kt < 16; ++kt) {
    const int k0 = kt * 64;
    __syncthreads();
#pragma unroll
    for (int p = 0; p < 4; ++p) {
      int idx = p * 256 + tid;
      int row = idx >> 3, ch = idx & 7;
      int gch = ch ^ (row & 7);
      gload_lds16(xb + (tm * 128 + row) * 1024 + k0 + gch * 8, (char*)lA + idx * 16);
    }
#pragma unroll
    for (int p = 0; p < 4; ++p) {
      int idx = p * 256 + tid;
      int row = idx >> 3, ch = idx & 7;
      int gch = ch ^ (row & 7);
      gload_lds16(wb + (tn * 128 + row) * 1024 + k0 + gch * 8, (char*)lB + idx * 16);
    }
    __syncthreads();
#pragma unroll
    for (int kc = 0; kc < 2; ++kc) {
      short8 af[4], bfr[4];
#pragma unroll
      for (int m = 0; m < 4; ++m) {
        int row = wr * 64 + m * 16 + l15;
        int ch = (kc * 4 + lg) ^ (row & 7);
        af[m] = *reinterpret_cast<const short8*>((const char*)lA + row * 128 + ch * 16);
      }
#pragma unroll
      for (int n = 0; n < 4; ++n) {
        int row = wc * 64 + n * 16 + l15;
        int ch = (kc * 4 + lg) ^ (row & 7);
        bfr[n] = *reinterpret_cast<const short8*>((const char*)lB + row * 128 + ch * 16);
      }
#pragma unroll
      for (int m = 0; m < 4; ++m)
#pragma unroll
        for (int n = 0; n < 4; ++n)
          acc[m][n] = __builtin_amdgcn_mfma_f32_16x16x32_bf16(af[m], bfr[n], acc[m][n], 0, 0, 0);
    }
  }

  const int sec = tn >> 3;   // 0=q 1=k 2=v
#pragma unroll
  for (int m = 0; m < 4; ++m) {
#pragma unroll
    for (int n = 0; n < 4; ++n) {
      int gcol = tn * 128 + wc * 64 + n * 16 + l15;
      float bv = bias[gcol];
      int colin = gcol & 1023;
      int h = colin >> 6, d = colin & 63;
      f32x4 v = acc[m][n];
#pragma unroll
      for (int i = 0; i < 4; ++i) v[i] += bv;
      int rbase = tm * 128 + wr * 64 + m * 16 + lg * 4;
      if (sec == 2) {
        int b = rbase >> 11, t0 = rbase & 2047;   // 4 consecutive t, same b (rbase%4==0)
        short4v sv = { bf16r(v[0]), bf16r(v[1]), bf16r(v[2]), bf16r(v[3]) };
        *reinterpret_cast<short4v*>(vb + (((b * 16 + h) * 64 + d) * 2048) + t0) = sv;
      } else {
        int j = d >> 1;
        bool odd = d & 1;
        short* dst = (sec == 0) ? qb : kb;
        float scale = (sec == 0) ? 0.18033688f : 1.0f;  // (1/8)*log2e folded into q
#pragma unroll
        for (int i = 0; i < 4; ++i) {
          int grow = rbase + i;
          int t = grow & 2047;
          float2 cs = tab[t * 32 + j];
          float part = __shfl_xor(v[i], 1);
          float nv = odd ? (cs.y * part + cs.x * v[i]) : (cs.x * v[i] - cs.y * part);
          int b = grow >> 11;
          dst[(((b * 16 + h) * 2048 + t) << 6) + d] = bf16r(nv * scale);
        }
      }
    }
  }
}

// ---------------- Flash attention, swapped-QK^T ----------------
// 8 waves x 16 q-rows = 128 q/block; KVBLK=64 double-buffered; grid (16, 32).
// S^T = mfma(K, Q): C col = q = lane&15  ->  per-lane scalar m/l, in-lane row reduce.
// O^T = mfma(V^T, P^T) accumulated transposed; stores coalesce as float4.
__launch_bounds__(512, 4)
__global__ void attn_k(const short* __restrict__ qb, const short* __restrict__ kb,
                       const short* __restrict__ vtb, float* __restrict__ out) {
  __shared__ short lK[2][64 * 64];    // [kv][d], chunk-XOR swizzled via source
  __shared__ short lVT[2][64 * 64];   // [d][kv], chunk-XOR swizzled via source
  __shared__ short lP[8][16 * 64];    // per-wave P^T as [q][kv], chunk-XOR swizzled
  const int tid = threadIdx.x, l = tid & 63, w = tid >> 6;
  const int l15 = l & 15, lg = l >> 4;
  const int qt = blockIdx.x, bh = blockIdx.y;

  const short* kbase = kb + bh * 2048 * 64;
  const short* vtbase = vtb + bh * 64 * 2048;

  // staging: 512 threads x 16B = one full 64x64 bf16 tile per buffer
  const int srow = tid >> 3, sch = tid & 7;
  const int gch = sch ^ (srow & 7);
  const short* ksrc = kbase + srow * 64 + gch * 8;     // +kt*4096
  const short* vsrc = vtbase + srow * 2048 + gch * 8;  // +kt*64
  char* kdst[2] = { (char*)lK[0] + tid * 16, (char*)lK[1] + tid * 16 };
  char* vdst[2] = { (char*)lVT[0] + tid * 16, (char*)lVT[1] + tid * 16 };

  // Q B-frag (lane l15 = q column), q pre-scaled by log2e/8
  const int q = qt * 128 + w * 16 + l15;
  const short* qptr = qb + (bh * 2048 + q) * 64;
  short8 qf[2];
  qf[0] = *reinterpret_cast<const short8*>(qptr + lg * 8);
  qf[1] = *reinterpret_cast<const short8*>(qptr + 32 + lg * 8);

  f32x4 o[4] = {};
  float mval = -1e30f, lval = 0.f;
  char* pw = (char*)lP[w];
  const int pbase = l15 * 128;

  // prologue stage
  gload_lds16(ksrc, kdst[0]);
  gload_lds16(vsrc, vdst[0]);
  __syncthreads();

  for (int kt = 0; kt < 32; ++kt) {
    const int cur = kt & 1;
    if (kt < 31) {
      gload_lds16(ksrc + (kt + 1) * 4096, kdst[cur ^ 1]);
      gload_lds16(vsrc + (kt + 1) * 64, vdst[cur ^ 1]);
    }
    const char* lk = (const char*)lK[cur];
    const char* lv = (const char*)lVT[cur];

    // S^T[kv][q] : A = K tile (4 m-subtiles), B = Q
    f32x4 s[4] = {};
#pragma unroll
    for (int kc = 0; kc < 2; ++kc)
#pragma unroll
      for (int m = 0; m < 4; ++m) {
        int row = m * 16 + l15;
        short8 kf = *reinterpret_cast<const short8*>(lk + row * 128 + (((kc * 4 + lg) ^ (row & 7)) * 16));
        s[m] = __builtin_amdgcn_mfma_f32_16x16x32_bf16(kf, qf[kc], s[m], 0, 0, 0);
      }

    // row max: 16 in-lane + 2 shuffles (this lane owns q = l15)
    float rm = s[0][0];
#pragma unroll
    for (int m = 0; m < 4; ++m)
#pragma unroll
      for (int i = 0; i < 4; ++i) rm = fmaxf(rm, s[m][i]);
    rm = fmaxf(rm, __shfl_xor(rm, 16));
    rm = fmaxf(rm, __shfl_xor(rm, 32));

    // defer-max (T13): only rescale when some row grew by > 8 (log2 units)
    if (!__all(rm <= mval + 8.0f)) {
      float mn = fmaxf(mval, rm);
      float corr = fast_exp2(mval - mn);
      mval = mn;
      lval *= corr;
#pragma unroll
      for (int dt = 0; dt < 4; ++dt)
#pragma unroll
        for (int i = 0; i < 4; ++i) o[dt][i] *= corr;
    }

    // P = 2^(S - m), row sum
    float rs = 0.f;
#pragma unroll
    for (int m = 0; m < 4; ++m)
#pragma unroll
      for (int i = 0; i < 4; ++i) {
        s[m][i] = fast_exp2(s[m][i] - mval);
        rs += s[m][i];
      }
    rs += __shfl_xor(rs, 16);
    rs += __shfl_xor(rs, 32);
    lval += rs;

    // pack bf16 pairs -> per-wave P^T[q][kv] (u32 writes, chunk-XOR swizzle)
#pragma unroll
    for (int m = 0; m < 4; ++m)
#pragma unroll
      for (int j = 0; j < 2; ++j) {
        unsigned int v32 = packbf2(s[m][2 * j], s[m][2 * j + 1]);
        int kv = m * 16 + lg * 4 + 2 * j;
        *reinterpret_cast<unsigned int*>(
            pw + pbase + (((kv >> 3) ^ (l15 & 7)) * 16) + ((kv & 7) * 2)) = v32;
      }

    // O^T += V^T P^T
#pragma unroll
    for (int kc = 0; kc < 2; ++kc) {
      short8 pf = *reinterpret_cast<const short8*>(
          pw + pbase + (((kc * 4 + lg) ^ (l15 & 7)) * 16));
#pragma unroll
      for (int dt = 0; dt < 4; ++dt) {
        int row = dt * 16 + l15;
        short8 vf = *reinterpret_cast<const short8*>(lv + row * 128 + (((kc * 4 + lg) ^ (row & 7)) * 16));
        o[dt] = __builtin_amdgcn_mfma_f32_16x16x32_bf16(vf, pf, o[dt], 0, 0, 0);
      }
    }
    __syncthreads();   // next tile staged (vmcnt drained) + all waves done with cur
  }

  // epilogue: O^T C-frag col=q, row=d -> float4 stores (4 lanes cover one 64B line)
  float inv = 1.0f / lval;
  const int b = bh >> 4, h = bh & 15;
  float* op = out + ((b * 2048 + q) * 1024) + h * 64;
#pragma unroll
  for (int dt = 0; dt < 4; ++dt) {
    f32x4 r = { o[dt][0] * inv, o[dt][1] * inv, o[dt][2] * inv, o[dt][3] * inv };
    *reinterpret_cast<f32x4*>(op + dt * 16 + lg * 4) = r;
  }
}

// ---------------- launch ----------------
extern "C" void kernel_launch(void* const* d_in, const int* in_sizes, int n_in,
                              void* d_out, int out_size, void* d_ws, size_t ws_size,
                              hipStream_t stream) {
  const float* x    = (const float*)d_in[0];   // [2,2048,1024]
  const float* W    = (const float*)d_in[1];   // [3072,1024]
  const float* bias = (const float*)d_in[2];   // [3072]
  float* out = (float*)d_out;
  char* ws = (char*)d_ws;

  short*  xb   = (short*) (ws);                  //  8 MiB
  short*  wb   = (short*) (ws + 8388608);        //  6 MiB
  short*  qbuf = (short*) (ws + 14680064);       //  8 MiB q [bh][t][d] (pre-scaled)
  short*  kbuf = (short*) (ws + 23068672);       //  8 MiB k [bh][t][d]
  short*  vtbuf= (short*) (ws + 31457280);       //  8 MiB v TRANSPOSED [bh][d][t]
  float2* tab  = (float2*)(ws + 39845888);       //  512 KiB

  hipLaunchKernelGGL(cvt_bf16_k, dim3(2048), dim3(256), 0, stream, x, xb, 4194304);
  hipLaunchKernelGGL(cvt_bf16_k, dim3(1536), dim3(256), 0, stream, W, wb, 3145728);
  hipLaunchKernelGGL(rope_tab_k, dim3(256), dim3(256), 0, stream, tab);
  hipLaunchKernelGGL(qkv_gemm_k, dim3(768), dim3(256), 0, stream,
                     xb, wb, bias, tab, qbuf, kbuf, vtbuf);
  hipLaunchKernelGGL(attn_k, dim3(16, 32), dim3(512), 0, stream, qbuf, kbuf, vtbuf, out);
}